// Round 9
// baseline (288.120 us; speedup 1.0000x reference)
//
#include <hip/hip_runtime.h>
#include <hip/hip_bf16.h>
#include <math.h>

// Problem constants: x [8,256,64,64] fp32, N = 4096, C = 256, Cqk = 32.
#define B_   8
#define C_   256
#define N_   4096
// 1/sqrt(32) * log2(e): scores computed directly in log2 space -> exp2 only.
#define QSCALE_L2E 0.2550541451582815f
#define DEFER_THR  11.5f   // defer-max threshold in log2 units (~8 nats)

typedef __attribute__((ext_vector_type(8))) short bf16x8;   // 8 bf16 = 4 VGPRs
typedef __attribute__((ext_vector_type(4))) float f32x4;

__device__ __forceinline__ unsigned short bfu(float f) {
    __hip_bfloat16 h = __float2bfloat16(f);
    return __builtin_bit_cast(unsigned short, h);
}
// v_cvt_pk_bf16_f32: lo -> D[15:0], hi -> D[31:16] (single VALU op)
__device__ __forceinline__ unsigned cvtpk(float lo, float hi) {
    unsigned r;
    asm("v_cvt_pk_bf16_f32 %0, %1, %2" : "=v"(r) : "v"(lo), "v"(hi));
    return r;
}

// ---------------------------------------------------------------------------
// Kernel 0: one-time W -> bf16 prep. wbf layout: Wq[32*256] | Wk | Wv[256*256].
// ---------------------------------------------------------------------------
__global__ __launch_bounds__(256) void w_prep(
    const float* __restrict__ Wq, const float* __restrict__ Wk,
    const float* __restrict__ Wv, unsigned short* __restrict__ wbf)
{
    const int i = blockIdx.x * 256 + threadIdx.x;
    const int off = i * 4;
    float4 f;
    if (off < 32 * C_)            f = *reinterpret_cast<const float4*>(Wq + off);
    else if (off < 64 * C_)       f = *reinterpret_cast<const float4*>(Wk + off - 32 * C_);
    else                          f = *reinterpret_cast<const float4*>(Wv + off - 64 * C_);
    ushort4 u;
    u.x = bfu(f.x); u.y = bfu(f.y); u.z = bfu(f.z); u.w = bfu(f.w);
    *reinterpret_cast<ushort4*>(wbf + off) = u;
}

// ---------------------------------------------------------------------------
// Kernel 1: QKV projection via MFMA (unchanged from round 6/7/8).
// Outputs: q,k [b][n][32] bf16 (q pre-scaled by QSCALE_L2E), v [b][c][n] bf16.
// ---------------------------------------------------------------------------
__global__ __launch_bounds__(256, 2) void qkv_proj_mfma(
    const float* __restrict__ x, const unsigned short* __restrict__ wbf,
    const float* __restrict__ bq, const float* __restrict__ bk,
    const float* __restrict__ bv,
    unsigned short* __restrict__ q, unsigned short* __restrict__ k,
    unsigned short* __restrict__ v)
{
    const int b = blockIdx.y, n0 = blockIdx.x * 64;
    const int t = threadIdx.x;
    const int w = t >> 6, l = t & 63;
    const int li = l & 15, g = l >> 4;

    __shared__ unsigned short xT[64 * 256];     // 32 KB; reused as vS[256][64]
    __shared__ unsigned short qkS[2 * 64 * 32]; // 8 KB

    {
        const int n = t & 63;
        const int cq0 = t >> 6;
        const float* xb = x + ((size_t)b * C_) * N_ + n0 + n;
        #pragma unroll 4
        for (int s = 0; s < 16; ++s) {
            const int cq = cq0 + 4 * s;
            const float f0 = xb[(size_t)(cq * 4 + 0) * N_];
            const float f1 = xb[(size_t)(cq * 4 + 1) * N_];
            const float f2 = xb[(size_t)(cq * 4 + 2) * N_];
            const float f3 = xb[(size_t)(cq * 4 + 3) * N_];
            ushort4 pk;
            pk.x = bfu(f0); pk.y = bfu(f1); pk.z = bfu(f2); pk.w = bfu(f3);
            const int byte = n * 512 + (((cq >> 1) ^ (n & 7)) << 4) + (cq & 1) * 8;
            *reinterpret_cast<ushort4*>(reinterpret_cast<char*>(xT) + byte) = pk;
        }
    }
    __syncthreads();

    const unsigned short* wq_bf = wbf;
    const unsigned short* wk_bf = wbf + 32 * C_;
    const unsigned short* wv_bf = wbf + 64 * C_;

    const unsigned short* wqk_bf = (w < 2) ? wq_bf : wk_bf;
    const float* bqk = (w < 2) ? bq : bk;
    const float qscl = (w < 2) ? QSCALE_L2E : 1.0f;
    const int mt0 = (w & 1) * 2;
    const int ov0 = w * 64;

    f32x4 accv[4][4];
    f32x4 accq[2][2];
    const f32x4 z4 = {0.f, 0.f, 0.f, 0.f};
    #pragma unroll
    for (int a = 0; a < 4; ++a)
        #pragma unroll
        for (int c2 = 0; c2 < 4; ++c2) accv[a][c2] = z4;
    #pragma unroll
    for (int a = 0; a < 2; ++a)
        #pragma unroll
        for (int c2 = 0; c2 < 2; ++c2) accq[a][c2] = z4;

    #pragma unroll 2
    for (int kk = 0; kk < 8; ++kk) {
        bf16x8 xf[4];
        #pragma unroll
        for (int nt = 0; nt < 4; ++nt) {
            const int row = nt * 16 + li;
            const int byte = row * 512 + (((kk * 4 + g) ^ (row & 7)) << 4);
            xf[nt] = *reinterpret_cast<const bf16x8*>(
                reinterpret_cast<const char*>(xT) + byte);
        }
        #pragma unroll
        for (int ot = 0; ot < 4; ++ot) {
            const bf16x8 wV = *reinterpret_cast<const bf16x8*>(
                wv_bf + (size_t)(ov0 + ot * 16 + li) * C_ + kk * 32 + g * 8);
            #pragma unroll
            for (int nt = 0; nt < 4; ++nt)
                accv[nt][ot] = __builtin_amdgcn_mfma_f32_16x16x32_bf16(
                    xf[nt], wV, accv[nt][ot], 0, 0, 0);
        }
        #pragma unroll
        for (int ot = 0; ot < 2; ++ot) {
            const bf16x8 wA = *reinterpret_cast<const bf16x8*>(
                wqk_bf + (size_t)(ot * 16 + li) * C_ + kk * 32 + g * 8);
            #pragma unroll
            for (int m2 = 0; m2 < 2; ++m2)
                accq[ot][m2] = __builtin_amdgcn_mfma_f32_16x16x32_bf16(
                    wA, xf[mt0 + m2], accq[ot][m2], 0, 0, 0);
        }
    }

    __syncthreads();   // xT reads done: reuse as vS

    {
        const int qk = (w < 2) ? 0 : 1;
        #pragma unroll
        for (int ot = 0; ot < 2; ++ot) {
            const int d0 = ot * 16 + 4 * g;
            const float4 b4 = *reinterpret_cast<const float4*>(bqk + d0);
            const int slot = ot * 4 + g;
            #pragma unroll
            for (int m2 = 0; m2 < 2; ++m2) {
                const int n = (mt0 + m2) * 16 + li;
                ushort4 s4;
                s4.x = bfu((accq[ot][m2][0] + b4.x) * qscl);
                s4.y = bfu((accq[ot][m2][1] + b4.y) * qscl);
                s4.z = bfu((accq[ot][m2][2] + b4.z) * qscl);
                s4.w = bfu((accq[ot][m2][3] + b4.w) * qscl);
                const int byte = qk * 4096 + n * 64 + ((slot ^ (n & 7)) << 3);
                *reinterpret_cast<ushort4*>(reinterpret_cast<char*>(qkS) + byte) = s4;
            }
        }
    }
    {
        #pragma unroll
        for (int ot = 0; ot < 4; ++ot) {
            const int o = ov0 + ot * 16 + li;
            const float bias = bv[o];
            #pragma unroll
            for (int nt = 0; nt < 4; ++nt) {
                ushort4 s4;
                s4.x = bfu(accv[nt][ot][0] + bias);
                s4.y = bfu(accv[nt][ot][1] + bias);
                s4.z = bfu(accv[nt][ot][2] + bias);
                s4.w = bfu(accv[nt][ot][3] + bias);
                const int slot = nt * 4 + g;
                const int byte = o * 128 + ((slot ^ (o & 7)) << 3);
                *reinterpret_cast<ushort4*>(reinterpret_cast<char*>(xT) + byte) = s4;
            }
        }
    }
    __syncthreads();

    {
        const char* qks = reinterpret_cast<const char*>(qkS);
        #pragma unroll
        for (int qk = 0; qk < 2; ++qk) {
            const int n = t >> 2, s2 = (t & 3) * 2;
            const int byteA = qk * 4096 + n * 64 + (((s2    ) ^ (n & 7)) << 3);
            const int byteB = qk * 4096 + n * 64 + (((s2 + 1) ^ (n & 7)) << 3);
            const uint2 lo = *reinterpret_cast<const uint2*>(qks + byteA);
            const uint2 hi = *reinterpret_cast<const uint2*>(qks + byteB);
            uint4 val = make_uint4(lo.x, lo.y, hi.x, hi.y);
            unsigned short* dst = (qk == 0) ? q : k;
            *reinterpret_cast<uint4*>(dst + ((size_t)b * N_ + n0) * 32 + t * 8) = val;
        }
    }
    {
        const char* vs = reinterpret_cast<const char*>(xT);
        #pragma unroll
        for (int p2 = 0; p2 < 8; ++p2) {
            const int o = p2 * 32 + (t >> 3);
            const int s2 = (t & 7) * 2;
            const int byteA = o * 128 + (((s2    ) ^ (o & 7)) << 3);
            const int byteB = o * 128 + (((s2 + 1) ^ (o & 7)) << 3);
            const uint2 lo = *reinterpret_cast<const uint2*>(vs + byteA);
            const uint2 hi = *reinterpret_cast<const uint2*>(vs + byteB);
            uint4 val = make_uint4(lo.x, lo.y, hi.x, hi.y);
            *reinterpret_cast<uint4*>(v + ((size_t)b * C_ + o) * N_ + n0 + (t & 7) * 8) = val;
        }
    }
}

// ---------------------------------------------------------------------------
// Kernel 2: flash attention, SMALL blocks for multi-block de-phasing.
// grid 1024 (b = id&7 -> XCD-local, i0 = (id>>3)*32), 256 threads (4 waves),
// launch_bounds(256,4) -> target 4 independent blocks/CU (16 waves/CU).
// Wave w: QS = w&1 (16 queries), JH = w>>1 (64 of 128 j), PV c-slice w*64.
// r7-proven 2-barrier flow, all LDS single-buffered (~17 KB). VGPR diet:
// acc[4][2]=32, V regs phased 8+8 (vA[4][2], kt23 issued mid-PV), K staged
// via 2 regs, early cvt_pk. Counted vmcnt: 2 (V-kt01 drained, K in flight),
// 0 mid-iter (kt23+K), 8 at peel.
// ---------------------------------------------------------------------------
__global__ __launch_bounds__(256, 4) void attn_mfma(
    const unsigned short* __restrict__ q, const unsigned short* __restrict__ k,
    const unsigned short* __restrict__ v,
    const float* __restrict__ x, const float* __restrict__ gamma,
    float* __restrict__ out)
{
    const int id = blockIdx.x;
    const int b = id & 7;                 // batch == XCD
    const int i0 = (id >> 3) * 32;
    const int t = threadIdx.x;
    const int w = t >> 6, l = t & 63;
    const int li = l & 15, g = l >> 4;
    const int QS = w & 1;                 // qslice (16 queries)
    const int JH = w >> 1;                // j-half (64 of 128 j)
    const int cw0 = w * 64;               // PV c-slice base

    __shared__ unsigned short kT[128 * 32];      // 8 KB K tile (single)
    __shared__ unsigned short pS[2][4][64 * 8];  // 8 KB P frags [qs][kt]
    __shared__ float mx_s[2][2][16];             // tile max [qs][jh][i]
    __shared__ float f_s[2][16];
    __shared__ int   flag_s[2];
    __shared__ float l_s[2][2][16];

    const unsigned short* qb = q + (size_t)b * N_ * 32;
    const unsigned short* kb = k + (size_t)b * N_ * 32;
    const unsigned short* vb = v + ((size_t)b * C_) * N_;

    // Q B-frag for own qslice: i = i0 + QS*16 + li
    const bf16x8 qf = *reinterpret_cast<const bf16x8*>(
        qb + (size_t)(i0 + QS * 16 + li) * 32 + g * 8);

    f32x4 acc[4][2];   // [ct][it] : O^T[c][i], c-slice 64, i 32
    const f32x4 z4 = {0.f, 0.f, 0.f, 0.f};
    #pragma unroll
    for (int a = 0; a < 4; ++a) { acc[a][0] = z4; acc[a][1] = z4; }

    float m_run = -3.0e38f;
    float l_part = 0.f;

    // K staging (r6 pattern): thread t stages rows jr=t>>2 of each 64-half,
    // rows permuted so S^T D-frag (jt,g,r) is j_local = (jt>>1)*32+(jt&1)*4+8g+r.
    const int jr = t >> 2, sl = t & 3;
    const int jt_s = jr >> 4, gg = (jr >> 2) & 3, rr = jr & 3;
    const int jperm = (jt_s >> 1) * 32 + (jt_s & 1) * 4 + gg * 8 + rr;
    const int s_src = sl ^ (jr & 3);
    const int kvoff_sh = jperm * 32 + s_src * 8;
    const unsigned voffK0 = (unsigned)(kvoff_sh * 2);
    const unsigned voffK1 = (unsigned)((kvoff_sh + 64 * 32) * 2);

    // V voffsets: one per ct; kt handled by the 13-bit signed offset imm.
    unsigned voffV[4];
    #pragma unroll
    for (int ct = 0; ct < 4; ++ct)
        voffV[ct] = (unsigned)(((cw0 + ct * 16 + li) * N_ + g * 8) * 2);

    union PB { unsigned wo[4]; bf16x8 v8; };

    bf16x8 knx0, knx1;
    bf16x8 vA[4][2];

    // QK(jj) for own (QS, JH): 4 ds_read + 4 MFMA -> sT; publish tile max
    auto qk_and_max = [&](f32x4* sT) {
        const char* kbuf = reinterpret_cast<const char*>(&kT[0]) + JH * 4096;
        #pragma unroll
        for (int jt = 0; jt < 4; ++jt) {
            const int row = jt * 16 + li;
            const bf16x8 kA = *reinterpret_cast<const bf16x8*>(
                kbuf + row * 64 + ((g ^ (row & 3)) << 4));
            sT[jt] = __builtin_amdgcn_mfma_f32_16x16x32_bf16(kA, qf, z4, 0, 0, 0);
        }
        float fm0 = fmaxf(fmaxf(sT[0][0], sT[0][1]), fmaxf(sT[0][2], sT[0][3]));
        float fm1 = fmaxf(fmaxf(sT[1][0], sT[1][1]), fmaxf(sT[1][2], sT[1][3]));
        float fm2 = fmaxf(fmaxf(sT[2][0], sT[2][1]), fmaxf(sT[2][2], sT[2][3]));
        float fm3 = fmaxf(fmaxf(sT[3][0], sT[3][1]), fmaxf(sT[3][2], sT[3][3]));
        float mx = fmaxf(fmaxf(fm0, fm1), fmaxf(fm2, fm3));
        mx = fmaxf(mx, __shfl_xor(mx, 16));
        mx = fmaxf(mx, __shfl_xor(mx, 32));
        if (l < 16) mx_s[QS][JH][li] = mx;
    };

    // softmax finish (defer-max) + publish pS/f/flag; sT dies here (early pack)
    auto sm_finish_publish = [&](f32x4* sT) {
        const float cand = fmaxf(mx_s[QS][0][li], mx_s[QS][1][li]);
        float f = 1.0f;
        const int any = __any(cand > m_run + DEFER_THR) ? 1 : 0;
        if (any) {
            const float mnew = fmaxf(m_run, cand);
            f = __builtin_amdgcn_exp2f(m_run - mnew);
            m_run = mnew;
            l_part *= f;
        }
        #pragma unroll
        for (int jt = 0; jt < 4; ++jt)
            #pragma unroll
            for (int r = 0; r < 4; ++r)
                sT[jt][r] = __builtin_amdgcn_exp2f(sT[jt][r] - m_run);
        const f32x4 sv = (sT[0] + sT[1]) + (sT[2] + sT[3]);
        l_part += (sv[0] + sv[1]) + (sv[2] + sv[3]);
        #pragma unroll
        for (int kt2 = 0; kt2 < 2; ++kt2) {   // global kt = JH*2 + kt2
            PB pk2;
            pk2.wo[0] = cvtpk(sT[2 * kt2][0],     sT[2 * kt2][1]);
            pk2.wo[1] = cvtpk(sT[2 * kt2][2],     sT[2 * kt2][3]);
            pk2.wo[2] = cvtpk(sT[2 * kt2 + 1][0], sT[2 * kt2 + 1][1]);
            pk2.wo[3] = cvtpk(sT[2 * kt2 + 1][2], sT[2 * kt2 + 1][3]);
            *reinterpret_cast<bf16x8*>(&pS[QS][JH * 2 + kt2][l * 8]) = pk2.v8;
        }
        if (JH == 0) {
            if (l < 16) f_s[QS][li] = f;
            if (l == 0) flag_s[QS] = any;
        }
    };

    // PV half: phase p covers kt = 2p, 2p+1 using vA[ct][0..1]
    auto pv_phase = [&](int p) {
        __builtin_amdgcn_s_setprio(1);
        #pragma unroll
        for (int k2 = 0; k2 < 2; ++k2) {
            const int kt = 2 * p + k2;
            const bf16x8 pb0 = *reinterpret_cast<const bf16x8*>(&pS[0][kt][l * 8]);
            const bf16x8 pb1 = *reinterpret_cast<const bf16x8*>(&pS[1][kt][l * 8]);
            #pragma unroll
            for (int ct = 0; ct < 4; ++ct) {
                acc[ct][0] = __builtin_amdgcn_mfma_f32_16x16x32_bf16(vA[ct][k2], pb0, acc[ct][0], 0, 0, 0);
                acc[ct][1] = __builtin_amdgcn_mfma_f32_16x16x32_bf16(vA[ct][k2], pb1, acc[ct][1], 0, 0, 0);
            }
        }
        __builtin_amdgcn_s_setprio(0);
    };
    // issue 8 V loads: kt pair (2p, 2p+1) of tile jj
    auto v_issue = [&](int jj, int p) {
        const unsigned short* sbv = vb + (size_t)jj * 128;
        if (p == 0) {
            #pragma unroll
            for (int ct = 0; ct < 4; ++ct)
                asm volatile("global_load_dwordx4 %0, %2, %3 offset:0\n\t"
                             "global_load_dwordx4 %1, %2, %3 offset:64"
                             : "=v"(vA[ct][0]), "=v"(vA[ct][1])
                             : "v"(voffV[ct]), "s"(sbv));
        } else {
            #pragma unroll
            for (int ct = 0; ct < 4; ++ct)
                asm volatile("global_load_dwordx4 %0, %2, %3 offset:128\n\t"
                             "global_load_dwordx4 %1, %2, %3 offset:192"
                             : "=v"(vA[ct][0]), "=v"(vA[ct][1])
                             : "v"(voffV[ct]), "s"(sbv));
        }
    };

    // ---- prologue: stage K(0) ----
    {
        const unsigned short* kst0 = kb + kvoff_sh;
        const bf16x8 a0 = *reinterpret_cast<const bf16x8*>(kst0);
        const bf16x8 a1 = *reinterpret_cast<const bf16x8*>(kst0 + 64 * 32);
        *reinterpret_cast<bf16x8*>(&kT[t * 8]) = a0;
        *reinterpret_cast<bf16x8*>(&kT[2048 + t * 8]) = a1;
    }
    __syncthreads();

    // ---- peel jj = 0 ----
    {
        const unsigned short* sbk = kb + 128 * 32;   // K(1)
        asm volatile("global_load_dwordx4 %0, %2, %4\n\t"
                     "global_load_dwordx4 %1, %3, %4"
                     : "=v"(knx0), "=v"(knx1)
                     : "v"(voffK0), "v"(voffK1), "s"(sbk));
        __builtin_amdgcn_sched_barrier(0);
        f32x4 sT[4];
        qk_and_max(sT);
        __syncthreads();                      // B(0): mx(0) visible
        sm_finish_publish(sT);
        v_issue(0, 0);                        // V(0) kt01
        __builtin_amdgcn_sched_barrier(0);
        asm volatile("s_waitcnt vmcnt(8)" ::: "memory");   // K(1) landed
        __builtin_amdgcn_sched_barrier(0);
        *reinterpret_cast<bf16x8*>(&kT[t * 8]) = knx0;
        *reinterpret_cast<bf16x8*>(&kT[2048 + t * 8]) = knx1;
    }

    // ---- main loop: iter jj does QK/SM(jj) + PV(jj-1), 2 barriers ----
    for (int jj = 1; jj < 32; ++jj) {
        __syncthreads();   // A: kT=K(jj), pS=P(jj-1), f/flag(jj-1) visible

        // issue K(jj+1)
        {
            const unsigned short* sbk = kb + (size_t)((jj == 31) ? 0 : (jj + 1)) * 128 * 32;
            asm volatile("global_load_dwordx4 %0, %2, %4\n\t"
                         "global_load_dwordx4 %1, %3, %4"
                         : "=v"(knx0), "=v"(knx1)
                         : "v"(voffK0), "v"(voffK1), "s"(sbk));
        }
        __builtin_amdgcn_sched_barrier(0);

        // QK(jj) + tile max publish
        f32x4 sT[4];
        qk_and_max(sT);

        // V(jj-1) kt01 landed (8 oldest); K(jj+1) stays in flight
        asm volatile("s_waitcnt vmcnt(2)" ::: "memory");
        __builtin_amdgcn_sched_barrier(0);

        // rescale acc by f(jj-1) (defer-max: usually skipped)
        #pragma unroll
        for (int it = 0; it < 2; ++it) {
            if (flag_s[it]) {
                const float ff = f_s[it][li];
                #pragma unroll
                for (int ct = 0; ct < 4; ++ct) acc[ct][it] *= ff;
            }
        }

        pv_phase(0);                          // PV(jj-1) kt01
        v_issue(jj - 1, 1);                   // V(jj-1) kt23 into vA
        __builtin_amdgcn_sched_barrier(0);
        asm volatile("s_waitcnt vmcnt(0)" ::: "memory");   // kt23 + K landed
        __builtin_amdgcn_sched_barrier(0);
        pv_phase(1);                          // PV(jj-1) kt23

        __syncthreads();   // B: mx(jj) visible; pS(jj-1) consumed by all

        sm_finish_publish(sT);                // pS(jj), f/flag(jj)
        v_issue(jj, 0);                       // V(jj) kt01
        __builtin_amdgcn_sched_barrier(0);

        // kT = K(jj+1): regs valid since the vmcnt(0) above
        *reinterpret_cast<bf16x8*>(&kT[t * 8]) = knx0;
        *reinterpret_cast<bf16x8*>(&kT[2048 + t * 8]) = knx1;
    }

    // ---- epilogue: PV(31) ----
    __syncthreads();   // pS(31), f/flag(31) visible
    #pragma unroll
    for (int it = 0; it < 2; ++it) {
        if (flag_s[it]) {
            const float ff = f_s[it][li];
            #pragma unroll
            for (int ct = 0; ct < 4; ++ct) acc[ct][it] *= ff;
        }
    }
    asm volatile("s_waitcnt vmcnt(0)" ::: "memory");   // V(31) kt01 landed
    __builtin_amdgcn_sched_barrier(0);
    pv_phase(0);
    v_issue(31, 1);
    __builtin_amdgcn_sched_barrier(0);
    asm volatile("s_waitcnt vmcnt(0)" ::: "memory");
    __builtin_amdgcn_sched_barrier(0);
    pv_phase(1);

    // ---- l: reduce over g, publish per (qslice, jhalf), sum halves ----
    float l_tot = l_part;
    l_tot += __shfl_xor(l_tot, 16);
    l_tot += __shfl_xor(l_tot, 32);
    if (l < 16) l_s[QS][JH][li] = l_tot;
    __syncthreads();

    const float gm = gamma[0];
    float linv[2];
    #pragma unroll
    for (int it = 0; it < 2; ++it)
        linv[it] = 1.0f / (l_s[it][0][li] + l_s[it][1][li]);

    const float* xb2 = x + ((size_t)b * C_) * N_;
    float* ob = out + ((size_t)b * C_) * N_;
    #pragma unroll
    for (int ct = 0; ct < 4; ++ct) {
        #pragma unroll
        for (int r = 0; r < 4; ++r) {
            const int c = cw0 + ct * 16 + 4 * g + r;
            #pragma unroll
            for (int it = 0; it < 2; ++it) {
                const int i = i0 + it * 16 + li;
                const size_t off = (size_t)c * N_ + i;
                ob[off] = gm * acc[ct][it][r] * linv[it] + xb2[off];
            }
        }
    }
}

// ---------------------------------------------------------------------------
// Workspace: q [8][4096][32] | k | v [8][256][4096] bf16 | wbf [320*256] bf16
// = 2 + 2 + 16 + 0.16 MB = ~20.2 MB in d_ws.
// ---------------------------------------------------------------------------
extern "C" void kernel_launch(void* const* d_in, const int* in_sizes, int n_in,
                              void* d_out, int out_size, void* d_ws, size_t ws_size,
                              hipStream_t stream) {
    const float* x     = (const float*)d_in[0];
    const float* Wq    = (const float*)d_in[1];
    const float* bq    = (const float*)d_in[2];
    const float* Wk    = (const float*)d_in[3];
    const float* bk    = (const float*)d_in[4];
    const float* Wv    = (const float*)d_in[5];
    const float* bv    = (const float*)d_in[6];
    const float* gamma = (const float*)d_in[7];
    float* out = (float*)d_out;

    unsigned short* q   = (unsigned short*)d_ws;
    unsigned short* k   = q + (size_t)B_ * N_ * 32;
    unsigned short* v   = k + (size_t)B_ * N_ * 32;
    unsigned short* wbf = v + (size_t)B_ * C_ * N_;

    dim3 grid(N_ / 64, B_);
    w_prep<<<80, 256, 0, stream>>>(Wq, Wk, Wv, wbf);
    qkv_proj_mfma<<<grid, 256, 0, stream>>>(x, wbf, bq, bk, bv, q, k, v);
    attn_mfma<<<1024, 256, 0, stream>>>(q, k, v, x, gamma, out);
}

// Round 10
// 156.212 us; speedup vs baseline: 1.8444x; 1.8444x over previous
//
#include <hip/hip_runtime.h>
#include <hip/hip_bf16.h>
#include <math.h>

// Problem constants: x [8,256,64,64] fp32, N = 4096, C = 256, Cqk = 32.
#define B_   8
#define C_   256
#define N_   4096
// 1/sqrt(32) * log2(e): scores computed directly in log2 space -> exp2 only.
#define QSCALE_L2E 0.2550541451582815f
#define DEFER_THR  11.5f   // defer-max threshold in log2 units (~8 nats)

typedef __attribute__((ext_vector_type(8))) short bf16x8;   // 8 bf16 = 4 VGPRs
typedef __attribute__((ext_vector_type(4))) float f32x4;

__device__ __forceinline__ unsigned short bfu(float f) {
    __hip_bfloat16 h = __float2bfloat16(f);
    return __builtin_bit_cast(unsigned short, h);
}
// v_cvt_pk_bf16_f32: lo -> D[15:0], hi -> D[31:16] (single VALU op)
__device__ __forceinline__ unsigned cvtpk(float lo, float hi) {
    unsigned r;
    asm("v_cvt_pk_bf16_f32 %0, %1, %2" : "=v"(r) : "v"(lo), "v"(hi));
    return r;
}

// ---------------------------------------------------------------------------
// Kernel 0: one-time W -> bf16 prep. wbf layout: Wq[32*256] | Wk | Wv[256*256].
// ---------------------------------------------------------------------------
__global__ __launch_bounds__(256) void w_prep(
    const float* __restrict__ Wq, const float* __restrict__ Wk,
    const float* __restrict__ Wv, unsigned short* __restrict__ wbf)
{
    const int i = blockIdx.x * 256 + threadIdx.x;
    const int off = i * 4;
    float4 f;
    if (off < 32 * C_)            f = *reinterpret_cast<const float4*>(Wq + off);
    else if (off < 64 * C_)       f = *reinterpret_cast<const float4*>(Wk + off - 32 * C_);
    else                          f = *reinterpret_cast<const float4*>(Wv + off - 64 * C_);
    ushort4 u;
    u.x = bfu(f.x); u.y = bfu(f.y); u.z = bfu(f.z); u.w = bfu(f.w);
    *reinterpret_cast<ushort4*>(wbf + off) = u;
}

// ---------------------------------------------------------------------------
// Kernel 1: QKV projection via MFMA (unchanged since round 6).
// Outputs: q,k [b][n][32] bf16 (q pre-scaled by QSCALE_L2E), v [b][c][n] bf16.
// ---------------------------------------------------------------------------
__global__ __launch_bounds__(256, 2) void qkv_proj_mfma(
    const float* __restrict__ x, const unsigned short* __restrict__ wbf,
    const float* __restrict__ bq, const float* __restrict__ bk,
    const float* __restrict__ bv,
    unsigned short* __restrict__ q, unsigned short* __restrict__ k,
    unsigned short* __restrict__ v)
{
    const int b = blockIdx.y, n0 = blockIdx.x * 64;
    const int t = threadIdx.x;
    const int w = t >> 6, l = t & 63;
    const int li = l & 15, g = l >> 4;

    __shared__ unsigned short xT[64 * 256];     // 32 KB; reused as vS[256][64]
    __shared__ unsigned short qkS[2 * 64 * 32]; // 8 KB

    {
        const int n = t & 63;
        const int cq0 = t >> 6;
        const float* xb = x + ((size_t)b * C_) * N_ + n0 + n;
        #pragma unroll 4
        for (int s = 0; s < 16; ++s) {
            const int cq = cq0 + 4 * s;
            const float f0 = xb[(size_t)(cq * 4 + 0) * N_];
            const float f1 = xb[(size_t)(cq * 4 + 1) * N_];
            const float f2 = xb[(size_t)(cq * 4 + 2) * N_];
            const float f3 = xb[(size_t)(cq * 4 + 3) * N_];
            ushort4 pk;
            pk.x = bfu(f0); pk.y = bfu(f1); pk.z = bfu(f2); pk.w = bfu(f3);
            const int byte = n * 512 + (((cq >> 1) ^ (n & 7)) << 4) + (cq & 1) * 8;
            *reinterpret_cast<ushort4*>(reinterpret_cast<char*>(xT) + byte) = pk;
        }
    }
    __syncthreads();

    const unsigned short* wq_bf = wbf;
    const unsigned short* wk_bf = wbf + 32 * C_;
    const unsigned short* wv_bf = wbf + 64 * C_;

    const unsigned short* wqk_bf = (w < 2) ? wq_bf : wk_bf;
    const float* bqk = (w < 2) ? bq : bk;
    const float qscl = (w < 2) ? QSCALE_L2E : 1.0f;
    const int mt0 = (w & 1) * 2;
    const int ov0 = w * 64;

    f32x4 accv[4][4];
    f32x4 accq[2][2];
    const f32x4 z4 = {0.f, 0.f, 0.f, 0.f};
    #pragma unroll
    for (int a = 0; a < 4; ++a)
        #pragma unroll
        for (int c2 = 0; c2 < 4; ++c2) accv[a][c2] = z4;
    #pragma unroll
    for (int a = 0; a < 2; ++a)
        #pragma unroll
        for (int c2 = 0; c2 < 2; ++c2) accq[a][c2] = z4;

    #pragma unroll 2
    for (int kk = 0; kk < 8; ++kk) {
        bf16x8 xf[4];
        #pragma unroll
        for (int nt = 0; nt < 4; ++nt) {
            const int row = nt * 16 + li;
            const int byte = row * 512 + (((kk * 4 + g) ^ (row & 7)) << 4);
            xf[nt] = *reinterpret_cast<const bf16x8*>(
                reinterpret_cast<const char*>(xT) + byte);
        }
        #pragma unroll
        for (int ot = 0; ot < 4; ++ot) {
            const bf16x8 wV = *reinterpret_cast<const bf16x8*>(
                wv_bf + (size_t)(ov0 + ot * 16 + li) * C_ + kk * 32 + g * 8);
            #pragma unroll
            for (int nt = 0; nt < 4; ++nt)
                accv[nt][ot] = __builtin_amdgcn_mfma_f32_16x16x32_bf16(
                    xf[nt], wV, accv[nt][ot], 0, 0, 0);
        }
        #pragma unroll
        for (int ot = 0; ot < 2; ++ot) {
            const bf16x8 wA = *reinterpret_cast<const bf16x8*>(
                wqk_bf + (size_t)(ot * 16 + li) * C_ + kk * 32 + g * 8);
            #pragma unroll
            for (int m2 = 0; m2 < 2; ++m2)
                accq[ot][m2] = __builtin_amdgcn_mfma_f32_16x16x32_bf16(
                    wA, xf[mt0 + m2], accq[ot][m2], 0, 0, 0);
        }
    }

    __syncthreads();   // xT reads done: reuse as vS

    {
        const int qk = (w < 2) ? 0 : 1;
        #pragma unroll
        for (int ot = 0; ot < 2; ++ot) {
            const int d0 = ot * 16 + 4 * g;
            const float4 b4 = *reinterpret_cast<const float4*>(bqk + d0);
            const int slot = ot * 4 + g;
            #pragma unroll
            for (int m2 = 0; m2 < 2; ++m2) {
                const int n = (mt0 + m2) * 16 + li;
                ushort4 s4;
                s4.x = bfu((accq[ot][m2][0] + b4.x) * qscl);
                s4.y = bfu((accq[ot][m2][1] + b4.y) * qscl);
                s4.z = bfu((accq[ot][m2][2] + b4.z) * qscl);
                s4.w = bfu((accq[ot][m2][3] + b4.w) * qscl);
                const int byte = qk * 4096 + n * 64 + ((slot ^ (n & 7)) << 3);
                *reinterpret_cast<ushort4*>(reinterpret_cast<char*>(qkS) + byte) = s4;
            }
        }
    }
    {
        #pragma unroll
        for (int ot = 0; ot < 4; ++ot) {
            const int o = ov0 + ot * 16 + li;
            const float bias = bv[o];
            #pragma unroll
            for (int nt = 0; nt < 4; ++nt) {
                ushort4 s4;
                s4.x = bfu(accv[nt][ot][0] + bias);
                s4.y = bfu(accv[nt][ot][1] + bias);
                s4.z = bfu(accv[nt][ot][2] + bias);
                s4.w = bfu(accv[nt][ot][3] + bias);
                const int slot = nt * 4 + g;
                const int byte = o * 128 + ((slot ^ (o & 7)) << 3);
                *reinterpret_cast<ushort4*>(reinterpret_cast<char*>(xT) + byte) = s4;
            }
        }
    }
    __syncthreads();

    {
        const char* qks = reinterpret_cast<const char*>(qkS);
        #pragma unroll
        for (int qk = 0; qk < 2; ++qk) {
            const int n = t >> 2, s2 = (t & 3) * 2;
            const int byteA = qk * 4096 + n * 64 + (((s2    ) ^ (n & 7)) << 3);
            const int byteB = qk * 4096 + n * 64 + (((s2 + 1) ^ (n & 7)) << 3);
            const uint2 lo = *reinterpret_cast<const uint2*>(qks + byteA);
            const uint2 hi = *reinterpret_cast<const uint2*>(qks + byteB);
            uint4 val = make_uint4(lo.x, lo.y, hi.x, hi.y);
            unsigned short* dst = (qk == 0) ? q : k;
            *reinterpret_cast<uint4*>(dst + ((size_t)b * N_ + n0) * 32 + t * 8) = val;
        }
    }
    {
        const char* vs = reinterpret_cast<const char*>(xT);
        #pragma unroll
        for (int p2 = 0; p2 < 8; ++p2) {
            const int o = p2 * 32 + (t >> 3);
            const int s2 = (t & 7) * 2;
            const int byteA = o * 128 + (((s2    ) ^ (o & 7)) << 3);
            const int byteB = o * 128 + (((s2 + 1) ^ (o & 7)) << 3);
            const uint2 lo = *reinterpret_cast<const uint2*>(vs + byteA);
            const uint2 hi = *reinterpret_cast<const uint2*>(vs + byteB);
            uint4 val = make_uint4(lo.x, lo.y, hi.x, hi.y);
            *reinterpret_cast<uint4*>(v + ((size_t)b * C_ + o) * N_ + n0 + (t & 7) * 8) = val;
        }
    }
}

// ---------------------------------------------------------------------------
// Kernel 2: flash attention, WAVE-INDEPENDENT (no P exchange). grid 512
// (b = id&7 -> XCD-local, i0 = (id>>3)*64), 256 threads (4 waves).
// Wave w owns queries i = i0 + w*16 + li END-TO-END: QK (4 MFMA, K from LDS),
// in-lane softmax (defer-max, no cross-lane common path), in-lane P pack
// (row-permuted K staging), PV over ALL 256 c (32 MFMA, V A-frags from LDS
// tile staged once per block, swizzled, <=2-way conflicts). Waves interact
// ONLY at the one double-buffer staging barrier per 64-j iteration.
// T14 staging: asm loads at iter top; vmcnt(0) + ds_write at iter bottom.
// LDS = 2*(4 + 32) KB = 72 KB -> 2 blocks/CU.
// ---------------------------------------------------------------------------
__global__ __launch_bounds__(256, 2) void attn_mfma(
    const unsigned short* __restrict__ q, const unsigned short* __restrict__ k,
    const unsigned short* __restrict__ v,
    const float* __restrict__ x, const float* __restrict__ gamma,
    float* __restrict__ out)
{
    const int id = blockIdx.x;
    const int b = id & 7;                 // batch == XCD
    const int i0 = (id >> 3) * 64;
    const int t = threadIdx.x;
    const int w = t >> 6, l = t & 63;
    const int li = l & 15, g = l >> 4;

    __shared__ unsigned short kT[2][64 * 32];    // 8 KB  (dbuf K tile)
    __shared__ unsigned short vT[2][256 * 64];   // 64 KB (dbuf V tile, swizzled)

    const unsigned short* qb = q + (size_t)b * N_ * 32;
    const unsigned short* kb = k + (size_t)b * N_ * 32;
    const unsigned short* vb = v + ((size_t)b * C_) * N_;

    // Q B-frag for own 16 queries: i = i0 + w*16 + li
    const bf16x8 qf = *reinterpret_cast<const bf16x8*>(
        qb + (size_t)(i0 + w * 16 + li) * 32 + g * 8);

    f32x4 acc[16];   // O^T[c][i]: c = ct*16 + 4g + r, i = own query (col li)
    const f32x4 z4 = {0.f, 0.f, 0.f, 0.f};
    #pragma unroll
    for (int a = 0; a < 16; ++a) acc[a] = z4;

    float m_run = -3.0e38f;
    float l_part = 0.f;

    // ---- K staging constants (r3-verified 64-row permutation) ----
    const int jr = t >> 2, sl = t & 3;
    const int jt_s = jr >> 4, gg = (jr >> 2) & 3, rr = jr & 3;
    const int jperm = (jt_s >> 1) * 32 + (jt_s & 1) * 4 + gg * 8 + rr;
    const int s_src = sl ^ (jr & 3);
    const int koff_sh = jperm * 32 + s_src * 8;        // shorts within K tile
    const unsigned voffK = (unsigned)(koff_sh * 2);    // bytes
    const int kdst_byte = t * 16;                      // jr*64 + sl*16

    // ---- V staging constants: pass p stages row vrow0 + p*64, chunk l&3 ----
    const int vrow0 = w * 16 + (l >> 2);
    const int vchunk = l & 3;
    unsigned voffVb[4];   // byte offsets into v[b] for (row, chunk), tile-relative
    int vdst[4][2];
    #pragma unroll
    for (int p = 0; p < 4; ++p) {
        const int row = vrow0 + p * 64;
        voffVb[p] = (unsigned)(((size_t)row * N_ + vchunk * 16) * 2);
        const int s0 = vchunk * 2;
        vdst[p][0] = row * 128 + (((s0    ) ^ (row & 7)) << 4);
        vdst[p][1] = row * 128 + (((s0 + 1) ^ (row & 7)) << 4);
    }

    union PB { unsigned wo[4]; bf16x8 v8; };

    // ---- prologue: stage K(0), V(0) into buffer 0 ----
    {
        const bf16x8 k0 = *reinterpret_cast<const bf16x8*>(
            reinterpret_cast<const char*>(kb) + voffK);
        *reinterpret_cast<bf16x8*>(reinterpret_cast<char*>(&kT[0][0]) + kdst_byte) = k0;
        #pragma unroll
        for (int p = 0; p < 4; ++p) {
            const char* src = reinterpret_cast<const char*>(vb) + voffVb[p];
            const bf16x8 a0 = *reinterpret_cast<const bf16x8*>(src);
            const bf16x8 a1 = *reinterpret_cast<const bf16x8*>(src + 16);
            *reinterpret_cast<bf16x8*>(reinterpret_cast<char*>(&vT[0][0]) + vdst[p][0]) = a0;
            *reinterpret_cast<bf16x8*>(reinterpret_cast<char*>(&vT[0][0]) + vdst[p][1]) = a1;
        }
    }
    __syncthreads();

    // ---- main loop: one barrier per 64-j tile; waves otherwise independent ----
    for (int jj = 0; jj < 64; ++jj) {
        const int cur = jj & 1, nxt = cur ^ 1;
        const bool pf = (jj + 1 < 64);

        // issue next-tile staging loads (held in regs until iter bottom: T14)
        bf16x8 knx;
        bf16x8 vnx[4][2];
        if (pf) {
            const unsigned short* sbk = kb + (size_t)(jj + 1) * 64 * 32;
            asm volatile("global_load_dwordx4 %0, %1, %2"
                         : "=v"(knx) : "v"(voffK), "s"(sbk));
            const unsigned short* sbv = vb + (size_t)(jj + 1) * 64;
            #pragma unroll
            for (int p = 0; p < 4; ++p)
                asm volatile("global_load_dwordx4 %0, %2, %3\n\t"
                             "global_load_dwordx4 %1, %2, %3 offset:16"
                             : "=v"(vnx[p][0]), "=v"(vnx[p][1])
                             : "v"(voffVb[p]), "s"(sbv));
            __builtin_amdgcn_sched_barrier(0);
        }

        // ---- QK: S^T[64 j][16 own i] = 4 MFMA ----
        f32x4 sT[4];
        {
            const char* kbuf = reinterpret_cast<const char*>(&kT[cur][0]);
            #pragma unroll
            for (int jt = 0; jt < 4; ++jt) {
                const int row = jt * 16 + li;
                const bf16x8 kA = *reinterpret_cast<const bf16x8*>(
                    kbuf + row * 64 + ((g ^ (row & 3)) << 4));
                sT[jt] = __builtin_amdgcn_mfma_f32_16x16x32_bf16(kA, qf, z4, 0, 0, 0);
            }
        }

        // ---- softmax (in-lane; cross-lane only on rare growth) ----
        float mx = fmaxf(fmaxf(fmaxf(sT[0][0], sT[0][1]), fmaxf(sT[0][2], sT[0][3])),
                         fmaxf(fmaxf(sT[1][0], sT[1][1]), fmaxf(sT[1][2], sT[1][3])));
        mx = fmaxf(mx, fmaxf(fmaxf(fmaxf(sT[2][0], sT[2][1]), fmaxf(sT[2][2], sT[2][3])),
                             fmaxf(fmaxf(sT[3][0], sT[3][1]), fmaxf(sT[3][2], sT[3][3]))));
        if (__any(mx > m_run + DEFER_THR)) {
            float mw = fmaxf(mx, __shfl_xor(mx, 16));
            mw = fmaxf(mw, __shfl_xor(mw, 32));
            const float mnew = fmaxf(m_run, mw);
            const float f = __builtin_amdgcn_exp2f(m_run - mnew);
            m_run = mnew;
            l_part *= f;
            #pragma unroll
            for (int ct = 0; ct < 16; ++ct) acc[ct] *= f;
        }
        #pragma unroll
        for (int jt = 0; jt < 4; ++jt)
            #pragma unroll
            for (int r = 0; r < 4; ++r)
                sT[jt][r] = __builtin_amdgcn_exp2f(sT[jt][r] - m_run);
        const f32x4 sv = (sT[0] + sT[1]) + (sT[2] + sT[3]);
        l_part += (sv[0] + sv[1]) + (sv[2] + sv[3]);

        // ---- pack P into PV B-frags (in-lane, r3-verified mapping) ----
        PB pb0, pb1;
        pb0.wo[0] = cvtpk(sT[0][0], sT[0][1]); pb0.wo[1] = cvtpk(sT[0][2], sT[0][3]);
        pb0.wo[2] = cvtpk(sT[1][0], sT[1][1]); pb0.wo[3] = cvtpk(sT[1][2], sT[1][3]);
        pb1.wo[0] = cvtpk(sT[2][0], sT[2][1]); pb1.wo[1] = cvtpk(sT[2][2], sT[2][3]);
        pb1.wo[2] = cvtpk(sT[3][0], sT[3][1]); pb1.wo[3] = cvtpk(sT[3][2], sT[3][3]);

        // ---- PV: all 256 c for own 16 queries; V A-frags from LDS ----
        __builtin_amdgcn_s_setprio(1);
        {
            const char* vbuf = reinterpret_cast<const char*>(&vT[cur][0]);
            #pragma unroll
            for (int ct = 0; ct < 16; ++ct) {
                const int vrow = ct * 16 + li;
                const bf16x8 vA0 = *reinterpret_cast<const bf16x8*>(
                    vbuf + vrow * 128 + (((g    ) ^ (vrow & 7)) << 4));
                const bf16x8 vA1 = *reinterpret_cast<const bf16x8*>(
                    vbuf + vrow * 128 + (((4 + g) ^ (vrow & 7)) << 4));
                acc[ct] = __builtin_amdgcn_mfma_f32_16x16x32_bf16(vA0, pb0.v8, acc[ct], 0, 0, 0);
                acc[ct] = __builtin_amdgcn_mfma_f32_16x16x32_bf16(vA1, pb1.v8, acc[ct], 0, 0, 0);
            }
        }
        __builtin_amdgcn_s_setprio(0);

        // ---- write staged K/V to the other buffer ----
        if (pf) {
            asm volatile("s_waitcnt vmcnt(0)" ::: "memory");
            __builtin_amdgcn_sched_barrier(0);
            *reinterpret_cast<bf16x8*>(
                reinterpret_cast<char*>(&kT[nxt][0]) + kdst_byte) = knx;
            char* vd = reinterpret_cast<char*>(&vT[nxt][0]);
            #pragma unroll
            for (int p = 0; p < 4; ++p) {
                *reinterpret_cast<bf16x8*>(vd + vdst[p][0]) = vnx[p][0];
                *reinterpret_cast<bf16x8*>(vd + vdst[p][1]) = vnx[p][1];
            }
        }
        __syncthreads();
    }

    // ---- l: reduce per-lane partials across g (lanes of same query) ----
    float l_tot = l_part;
    l_tot += __shfl_xor(l_tot, 16);
    l_tot += __shfl_xor(l_tot, 32);
    const float linv = 1.0f / l_tot;

    const float gm = gamma[0];
    const int i = i0 + w * 16 + li;
    const float* xb2 = x + ((size_t)b * C_) * N_ + i;
    float* ob = out + ((size_t)b * C_) * N_ + i;
    #pragma unroll
    for (int ct = 0; ct < 16; ++ct) {
        #pragma unroll
        for (int r = 0; r < 4; ++r) {
            const int c = ct * 16 + 4 * g + r;
            const size_t off = (size_t)c * N_;
            ob[off] = gm * acc[ct][r] * linv + xb2[off];
        }
    }
}

// ---------------------------------------------------------------------------
// Workspace: q [8][4096][32] | k | v [8][256][4096] bf16 | wbf [320*256] bf16
// = 2 + 2 + 16 + 0.16 MB = ~20.2 MB in d_ws.
// ---------------------------------------------------------------------------
extern "C" void kernel_launch(void* const* d_in, const int* in_sizes, int n_in,
                              void* d_out, int out_size, void* d_ws, size_t ws_size,
                              hipStream_t stream) {
    const float* x     = (const float*)d_in[0];
    const float* Wq    = (const float*)d_in[1];
    const float* bq    = (const float*)d_in[2];
    const float* Wk    = (const float*)d_in[3];
    const float* bk    = (const float*)d_in[4];
    const float* Wv    = (const float*)d_in[5];
    const float* bv    = (const float*)d_in[6];
    const float* gamma = (const float*)d_in[7];
    float* out = (float*)d_out;

    unsigned short* q   = (unsigned short*)d_ws;
    unsigned short* k   = q + (size_t)B_ * N_ * 32;
    unsigned short* v   = k + (size_t)B_ * N_ * 32;
    unsigned short* wbf = v + (size_t)B_ * C_ * N_;

    dim3 grid(N_ / 64, B_);
    w_prep<<<80, 256, 0, stream>>>(Wq, Wk, Wv, wbf);
    qkv_proj_mfma<<<grid, 256, 0, stream>>>(x, wbf, bq, bk, bv, q, k, v);
    attn_mfma<<<512, 256, 0, stream>>>(q, k, v, x, gamma, out);
}